// Round 1
// baseline (1417.930 us; speedup 1.0000x reference)
//
#include <hip/hip_runtime.h>

#define HW   56
#define CIN  64
#define OC   512
#define NPIX (HW * HW)   // 3136

// ---------------------------------------------------------------------------
// Kernel 1: 3x3 conv (pad=1, stride=1), NCHW input -> [b][h][w][o] output.
// Block: 128 threads, covers (b, 64-oc tile "ot", h-pair, all 56 w).
// Each thread: 4 oc x 14 w accumulators.
// ---------------------------------------------------------------------------
#define CK 16          // input-channel chunk staged per iteration
#define WLS 145        // padded LDS stride for weights (144 -> 2-bank disaster)

__global__ __launch_bounds__(128)
void conv3x3_kernel(const float* __restrict__ x, const float* __restrict__ Wc,
                    float* __restrict__ y) {
  __shared__ float xl[CK][4][64];        // 16 KB  (rows h0-1 .. h0+2, w padded)
  __shared__ float wl[64 * WLS];         // 37.1 KB

  const int tid = threadIdx.x;
  const int h0  = blockIdx.x * 2;
  const int ot  = blockIdx.y;
  const int b   = blockIdx.z;

  const int wg    = tid & 3;             // w-group: 14 outputs each
  const int hh    = (tid >> 2) & 1;      // which of the 2 h rows
  const int og    = tid >> 3;            // oc group (0..15), 4 oc each
  const int wbase = wg * 14;

  float acc[4][14];
  #pragma unroll
  for (int j = 0; j < 4; ++j)
    #pragma unroll
    for (int i = 0; i < 14; ++i) acc[j][i] = 0.f;

  for (int cb = 0; cb < CIN; cb += CK) {
    // zero the two pad columns actually read (idx 0 and 57); 128 entries, one/thread
    {
      int c = tid >> 3, r = (tid >> 1) & 3, side = tid & 1;
      xl[c][r][side ? 57 : 0] = 0.f;
    }
    // stage x rows h0-1 .. h0+2 for this channel chunk
    for (int idx = tid; idx < CK * 4 * HW; idx += 128) {
      int w  = idx % HW;
      int t2 = idx / HW;
      int r  = t2 & 3;
      int c  = t2 >> 2;
      int gh = h0 - 1 + r;
      float v = 0.f;
      if (gh >= 0 && gh < HW)
        v = x[((b * CIN + cb + c) * HW + gh) * HW + w];
      xl[c][r][1 + w] = v;
    }
    // stage weights: 64 oc x (CK*9) contiguous runs
    for (int idx = tid; idx < 64 * CK * 9; idx += 128) {
      int oc  = idx / (CK * 9);
      int rem = idx - oc * (CK * 9);
      wl[oc * WLS + rem] = Wc[(ot * 64 + oc) * 576 + cb * 9 + rem];
    }
    __syncthreads();

    for (int c = 0; c < CK; ++c) {
      #pragma unroll
      for (int r = 0; r < 3; ++r) {
        float xv[16];
        #pragma unroll
        for (int i = 0; i < 16; ++i) xv[i] = xl[c][hh + r][wbase + i];
        #pragma unroll
        for (int j = 0; j < 4; ++j) {
          #pragma unroll
          for (int kw = 0; kw < 3; ++kw) {
            float wv = wl[(og * 4 + j) * WLS + c * 9 + r * 3 + kw];
            #pragma unroll
            for (int i = 0; i < 14; ++i)
              acc[j][i] += wv * xv[i + kw];
          }
        }
      }
    }
    __syncthreads();  // protect next chunk's staging
  }

  // store: y[((b*56+h)*56+w)*512 + o], 4 consecutive oc -> float4
  const int h = h0 + hh;
  #pragma unroll
  for (int i = 0; i < 14; ++i) {
    int w = wbase + i;
    size_t base = ((size_t)(b * HW + h) * HW + w) * OC + ot * 64 + og * 4;
    float4 o4 = make_float4(acc[0][i], acc[1][i], acc[2][i], acc[3][i]);
    *(float4*)&y[base] = o4;
  }
}

// ---------------------------------------------------------------------------
// Kernel 2: per-pixel channel attention + 1x1 conv + ReLU.
// One 256-thread block per (b, pixel). q/k/v laid out [b][h][w][o], o = n*64+c.
// ---------------------------------------------------------------------------
__global__ __launch_bounds__(256)
void attn_kernel(const float* __restrict__ q, const float* __restrict__ k,
                 const float* __restrict__ v, const float* __restrict__ Wu,
                 float* __restrict__ out) {
  __shared__ float ql[512];          // q[c][n] at ql[c*8+n]; later reused for attended
  __shared__ float kl[512];
  __shared__ float vl[512];
  __shared__ float sc[64 * 65];      // scores [qc][kc], stride 65 (bank-safe rows)
  __shared__ float al[64 * 64];      // attn transposed: al[kc*64+qc]

  const int tid = threadIdx.x;
  const int pix = blockIdx.x;
  const int b   = blockIdx.y;
  const size_t base = ((size_t)b * NPIX + pix) * 512;

  // stage q/k/v, transposing o=n*64+c -> [c][n]
  for (int o = tid; o < 512; o += 256) {
    int dst = (o & 63) * 8 + (o >> 6);
    ql[dst] = q[base + o];
    kl[dst] = k[base + o];
    vl[dst] = v[base + o];
  }
  __syncthreads();

  // ---- scores: S[qc][kc] = scale * sum_n q[qc][n] k[kc][n]; 4x4 tile/thread
  {
    const int tq = tid >> 4, tk = tid & 15;
    float qv[4][8], kv[4][8];
    #pragma unroll
    for (int a = 0; a < 4; ++a)
      #pragma unroll
      for (int n = 0; n < 8; ++n) {
        qv[a][n] = ql[(tq * 4 + a) * 8 + n];
        kv[a][n] = kl[(tk * 4 + a) * 8 + n];
      }
    float s[4][4];
    #pragma unroll
    for (int a = 0; a < 4; ++a)
      #pragma unroll
      for (int c2 = 0; c2 < 4; ++c2) s[a][c2] = 0.f;
    #pragma unroll
    for (int n = 0; n < 8; ++n)
      #pragma unroll
      for (int a = 0; a < 4; ++a)
        #pragma unroll
        for (int c2 = 0; c2 < 4; ++c2)
          s[a][c2] += qv[a][n] * kv[c2][n];
    const float scale = 0.044194173824159216f;  // 1/sqrt(512)
    #pragma unroll
    for (int a = 0; a < 4; ++a)
      #pragma unroll
      for (int c2 = 0; c2 < 4; ++c2)
        sc[(tq * 4 + a) * 65 + tk * 4 + c2] = s[a][c2] * scale;
  }
  __syncthreads();

  // ---- softmax over kc, one row per lane of wave 0; write transposed
  if (tid < 64) {
    const int qc = tid;
    float row[64];
    float m = -1e30f;
    #pragma unroll
    for (int kc = 0; kc < 64; ++kc) {
      row[kc] = sc[qc * 65 + kc];
      m = fmaxf(m, row[kc]);
    }
    float ssum = 0.f;
    #pragma unroll
    for (int kc = 0; kc < 64; ++kc) {
      float e = __expf(row[kc] - m);
      row[kc] = e;
      ssum += e;
    }
    float inv = 1.f / ssum;
    #pragma unroll
    for (int kc = 0; kc < 64; ++kc) al[kc * 64 + qc] = row[kc] * inv;
  }
  __syncthreads();

  // ---- attended[qc][n] = sum_kc attn[qc][kc] * v[kc][n]; 2 n per thread
  {
    const int qc = tid & 63, g = tid >> 6;
    float a0 = 0.f, a1 = 0.f;
    for (int kc = 0; kc < 64; ++kc) {
      float a  = al[kc * 64 + qc];
      float v0 = vl[kc * 8 + g * 2];
      float v1 = vl[kc * 8 + g * 2 + 1];
      a0 += a * v0;
      a1 += a * v1;
    }
    // all threads are past the last read of ql (scores phase + 2 barriers)
    ql[qc * 8 + g * 2]     = a0;   // attended flat index ci = qc*8 + n
    ql[qc * 8 + g * 2 + 1] = a1;
  }
  __syncthreads();

  // ---- out[co] = relu( sum_ci Wu[co][ci] * attended[ci] ); wave g does 16 co
  {
    const int l = tid & 63, g = tid >> 6;
    float av[8];
    #pragma unroll
    for (int j = 0; j < 8; ++j) av[j] = ql[j * 64 + l];
    #pragma unroll
    for (int ci = 0; ci < 16; ++ci) {
      int co = g * 16 + ci;
      float p = 0.f;
      #pragma unroll
      for (int j = 0; j < 8; ++j)
        p += Wu[co * 512 + j * 64 + l] * av[j];
      #pragma unroll
      for (int off = 32; off > 0; off >>= 1)
        p += __shfl_xor(p, off, 64);
      if (l == 0)
        out[((size_t)b * 64 + co) * NPIX + pix] = fmaxf(p, 0.f);
    }
  }
}

// ---------------------------------------------------------------------------
extern "C" void kernel_launch(void* const* d_in, const int* in_sizes, int n_in,
                              void* d_out, int out_size, void* d_ws, size_t ws_size,
                              hipStream_t stream) {
  const float* x  = (const float*)d_in[0];
  const float* Wq = (const float*)d_in[1];
  const float* Wk = (const float*)d_in[2];
  const float* Wv = (const float*)d_in[3];
  const float* Wu = (const float*)d_in[4];
  float* out = (float*)d_out;

  const size_t per = (size_t)8 * NPIX * 512;  // 12.85M floats per tensor
  float* q = (float*)d_ws;
  float* k = q + per;
  float* v = k + per;

  dim3 cgrid(HW / 2, 8, 8);  // (h-pairs, oc-tiles, batch)
  conv3x3_kernel<<<cgrid, 128, 0, stream>>>(x, Wq, q);
  conv3x3_kernel<<<cgrid, 128, 0, stream>>>(x, Wk, k);
  conv3x3_kernel<<<cgrid, 128, 0, stream>>>(x, Wv, v);

  attn_kernel<<<dim3(NPIX, 8), 256, 0, stream>>>(q, k, v, Wu, out);
}

// Round 2
// 517.053 us; speedup vs baseline: 2.7423x; 2.7423x over previous
//
#include <hip/hip_runtime.h>
#include <hip/hip_bf16.h>

#define HW   56
#define CIN  64
#define OC   512
#define NPIX (HW * HW)   // 3136

typedef unsigned short ushort_t;
typedef __attribute__((ext_vector_type(8))) short short8;
typedef __attribute__((ext_vector_type(4))) float floatx4;

// ---------------------------------------------------------------------------
// Prepass A: x NCHW fp32 -> xT [b][h][w][c] bf16.  Block per (h, b).
// ---------------------------------------------------------------------------
__global__ __launch_bounds__(256)
void cast_x_kernel(const float* __restrict__ x, ushort_t* __restrict__ xT) {
  __shared__ ushort_t lx[CIN * HW];   // [c][w]
  const int tid = threadIdx.x;
  const int h = blockIdx.x, b = blockIdx.y;
  // phase 1: coalesced read (w fastest), store [c][w]
  for (int idx = tid; idx < CIN * HW; idx += 256) {
    int c = idx / HW, w = idx - c * HW;
    float v = x[((size_t)(b * CIN + c) * HW + h) * HW + w];
    __hip_bfloat16 hb = __float2bfloat16(v);
    lx[idx] = *(ushort_t*)&hb;
  }
  __syncthreads();
  // phase 2: gather [w][c], write ushort4 coalesced
  ushort_t* dst = xT + ((size_t)(b * HW + h)) * HW * CIN;
  for (int i = tid; i < (CIN * HW) / 4; i += 256) {
    int e0 = i * 4;
    int w = e0 >> 6, c0 = e0 & 63;
    ushort4 o;
    o.x = lx[(c0 + 0) * HW + w];
    o.y = lx[(c0 + 1) * HW + w];
    o.z = lx[(c0 + 2) * HW + w];
    o.w = lx[(c0 + 3) * HW + w];
    ((ushort4*)dst)[i] = o;
  }
}

// ---------------------------------------------------------------------------
// Prepass B: W [oc][cin][3][3] fp32 -> Wb [tap][oc][cin] bf16 (3 tensors via z)
// ---------------------------------------------------------------------------
__global__ __launch_bounds__(64)
void cast_w_kernel(const float* __restrict__ W0, const float* __restrict__ W1,
                   const float* __restrict__ W2, ushort_t* __restrict__ D0,
                   ushort_t* __restrict__ D1, ushort_t* __restrict__ D2) {
  const int cin = threadIdx.x;
  const int oc = blockIdx.x, tap = blockIdx.y, sel = blockIdx.z;
  const float* W = sel == 0 ? W0 : (sel == 1 ? W1 : W2);
  ushort_t* D = sel == 0 ? D0 : (sel == 1 ? D1 : D2);
  float v = W[(size_t)oc * 576 + cin * 9 + tap];
  __hip_bfloat16 hb = __float2bfloat16(v);
  D[((size_t)tap * OC + oc) * CIN + cin] = *(ushort_t*)&hb;
}

// ---------------------------------------------------------------------------
// Kernel 1: 3x3 conv via MFMA 16x16x32 bf16 implicit GEMM.
// Block: 256 thr (4 waves). Tile: M=112 px (2 rows x 56 w), N=128 oc.
// Wave w owns oc-quarter w*32 (2 N-tiles), all 7 M-tiles.
// K-loop: 9 taps x 2 cin-chunks of 32.
// ---------------------------------------------------------------------------
#define XLS 72             // padded cin stride in x LDS tile (bf16 units)
#define XROW (58 * XLS)    // 4176
#define WLS 72             // padded cin stride in weight LDS

__global__ __launch_bounds__(256, 3)
void conv3x3_mfma(const ushort_t* __restrict__ xT, const ushort_t* __restrict__ Wb,
                  __hip_bfloat16* __restrict__ y) {
  __shared__ __align__(16) ushort_t xl[4 * XROW];   // 33408 B
  __shared__ __align__(16) ushort_t wl[128 * WLS];  // 18432 B

  const int tid  = threadIdx.x;
  const int lane = tid & 63;
  const int wv   = tid >> 6;       // wave id = oc quarter
  const int g    = blockIdx.x;     // row pair 0..27
  const int ob   = blockIdx.y;     // oc block 0..3
  const int b    = blockIdx.z;
  const int h0   = g * 2;
  const int l15  = lane & 15;
  const int quad = lane >> 4;

  // A-fragment LDS base (bf16 units) per M-tile: pixel t*16+l15
  int abase[7];
  #pragma unroll
  for (int t = 0; t < 7; ++t) {
    int pix = t * 16 + l15;
    int row = pix / HW, ww = pix - row * HW;
    abase[t] = (row * 58 + ww) * XLS + quad * 8;
  }
  // B-fragment LDS base per N-tile
  int bbase[2];
  #pragma unroll
  for (int nt = 0; nt < 2; ++nt)
    bbase[nt] = (wv * 32 + nt * 16 + l15) * WLS + quad * 8;

  floatx4 acc[7][2];
  #pragma unroll
  for (int t = 0; t < 7; ++t)
    #pragma unroll
    for (int nt = 0; nt < 2; ++nt) acc[t][nt] = (floatx4){0.f, 0.f, 0.f, 0.f};

  // ---- zero x tile (halos + possible out-of-range rows)
  for (int i = tid; i < (4 * XROW * 2) / 16; i += 256)
    ((uint4*)xl)[i] = (uint4){0, 0, 0, 0};
  __syncthreads();

  // ---- stage x rows h0-1 .. h0+2 (valid ones), [row][1+w][c]
  for (int r = 0; r < 4; ++r) {
    int gh = h0 - 1 + r;
    if (gh >= 0 && gh < HW) {
      const uint4* src = (const uint4*)(xT + ((size_t)(b * HW + gh) * HW) * CIN);
      for (int idx = tid; idx < 448; idx += 256) {   // 56 w x 8 chunks of 8 bf16
        int w = idx >> 3, co = (idx & 7) * 8;
        uint4 d = src[idx];
        *(uint4*)&xl[(r * 58 + 1 + w) * XLS + co] = d;
      }
    }
  }
  // (first tap's two barriers below order this before any MFMA read)

  const ushort_t* wsrc_base = Wb + (size_t)ob * 128 * CIN;

  #pragma unroll
  for (int kh = 0; kh < 3; ++kh) {
    #pragma unroll
    for (int kw = 0; kw < 3; ++kw) {
      const int tap = kh * 3 + kw;
      __syncthreads();   // previous tap's reads done (tap0: x staging visible)
      {
        const uint4* wsrc = (const uint4*)(wsrc_base + (size_t)tap * OC * CIN);
        #pragma unroll
        for (int i = 0; i < 4; ++i) {
          int idx = tid + i * 256;          // 0..1023 chunks of 8 bf16
          int oc = idx >> 3, co = (idx & 7) * 8;
          uint4 d = wsrc[idx];
          *(uint4*)&wl[oc * WLS + co] = d;
        }
      }
      __syncthreads();

      #pragma unroll
      for (int ck = 0; ck < 2; ++ck) {
        const int cko = ck * 32;
        short8 bf[2];
        #pragma unroll
        for (int nt = 0; nt < 2; ++nt)
          bf[nt] = *(const short8*)&wl[bbase[nt] + cko];
        #pragma unroll
        for (int t = 0; t < 7; ++t) {
          short8 af = *(const short8*)&xl[abase[t] + (kh * 58 + kw) * XLS + cko];
          #pragma unroll
          for (int nt = 0; nt < 2; ++nt)
            acc[t][nt] = __builtin_amdgcn_mfma_f32_16x16x32_bf16(
                af, bf[nt], acc[t][nt], 0, 0, 0);
        }
      }
    }
  }

  // ---- epilogue: D row = quad*4+r (pixel), col = l15 (oc)
  #pragma unroll
  for (int t = 0; t < 7; ++t) {
    #pragma unroll
    for (int r = 0; r < 4; ++r) {
      int pix = t * 16 + quad * 4 + r;
      int row = pix / HW, ww = pix - row * HW;
      size_t out = ((size_t)((b * HW + h0 + row) * HW + ww)) * OC + ob * 128 + wv * 32;
      #pragma unroll
      for (int nt = 0; nt < 2; ++nt)
        y[out + nt * 16 + l15] = __float2bfloat16(acc[t][nt][r]);
    }
  }
}

// ---------------------------------------------------------------------------
// Kernel 2: per-pixel channel attention + 1x1 conv + ReLU (q/k/v now bf16).
// ---------------------------------------------------------------------------
__global__ __launch_bounds__(256)
void attn_kernel(const __hip_bfloat16* __restrict__ q, const __hip_bfloat16* __restrict__ k,
                 const __hip_bfloat16* __restrict__ v, const float* __restrict__ Wu,
                 float* __restrict__ out) {
  __shared__ float ql[512];          // q[c][n]; later reused for attended
  __shared__ float kl[512];
  __shared__ float vl[512];
  __shared__ float sc[64 * 65];      // scores [qc][kc]
  __shared__ float al[64 * 64];      // attn transposed al[kc*64+qc]

  const int tid = threadIdx.x;
  const int pix = blockIdx.x;
  const int b   = blockIdx.y;
  const size_t base = ((size_t)b * NPIX + pix) * 512;

  for (int o = tid; o < 512; o += 256) {
    int dst = (o & 63) * 8 + (o >> 6);
    ql[dst] = __bfloat162float(q[base + o]);
    kl[dst] = __bfloat162float(k[base + o]);
    vl[dst] = __bfloat162float(v[base + o]);
  }
  __syncthreads();

  {
    const int tq = tid >> 4, tk = tid & 15;
    float qv[4][8], kv[4][8];
    #pragma unroll
    for (int a = 0; a < 4; ++a)
      #pragma unroll
      for (int n = 0; n < 8; ++n) {
        qv[a][n] = ql[(tq * 4 + a) * 8 + n];
        kv[a][n] = kl[(tk * 4 + a) * 8 + n];
      }
    float s[4][4];
    #pragma unroll
    for (int a = 0; a < 4; ++a)
      #pragma unroll
      for (int c2 = 0; c2 < 4; ++c2) s[a][c2] = 0.f;
    #pragma unroll
    for (int n = 0; n < 8; ++n)
      #pragma unroll
      for (int a = 0; a < 4; ++a)
        #pragma unroll
        for (int c2 = 0; c2 < 4; ++c2)
          s[a][c2] += qv[a][n] * kv[c2][n];
    const float scale = 0.044194173824159216f;  // 1/sqrt(512)
    #pragma unroll
    for (int a = 0; a < 4; ++a)
      #pragma unroll
      for (int c2 = 0; c2 < 4; ++c2)
        sc[(tq * 4 + a) * 65 + tk * 4 + c2] = s[a][c2] * scale;
  }
  __syncthreads();

  if (tid < 64) {
    const int qc = tid;
    float row[64];
    float m = -1e30f;
    #pragma unroll
    for (int kc = 0; kc < 64; ++kc) {
      row[kc] = sc[qc * 65 + kc];
      m = fmaxf(m, row[kc]);
    }
    float ssum = 0.f;
    #pragma unroll
    for (int kc = 0; kc < 64; ++kc) {
      float e = __expf(row[kc] - m);
      row[kc] = e;
      ssum += e;
    }
    float inv = 1.f / ssum;
    #pragma unroll
    for (int kc = 0; kc < 64; ++kc) al[kc * 64 + qc] = row[kc] * inv;
  }
  __syncthreads();

  {
    const int qc = tid & 63, g = tid >> 6;
    float a0 = 0.f, a1 = 0.f;
    for (int kc = 0; kc < 64; ++kc) {
      float a  = al[kc * 64 + qc];
      a0 += a * vl[kc * 8 + g * 2];
      a1 += a * vl[kc * 8 + g * 2 + 1];
    }
    ql[qc * 8 + g * 2]     = a0;
    ql[qc * 8 + g * 2 + 1] = a1;
  }
  __syncthreads();

  {
    const int l = tid & 63, g = tid >> 6;
    float av[8];
    #pragma unroll
    for (int j = 0; j < 8; ++j) av[j] = ql[j * 64 + l];
    #pragma unroll
    for (int ci = 0; ci < 16; ++ci) {
      int co = g * 16 + ci;
      float p = 0.f;
      #pragma unroll
      for (int j = 0; j < 8; ++j)
        p += Wu[co * 512 + j * 64 + l] * av[j];
      #pragma unroll
      for (int off = 32; off > 0; off >>= 1)
        p += __shfl_xor(p, off, 64);
      if (l == 0)
        out[((size_t)b * 64 + co) * NPIX + pix] = fmaxf(p, 0.f);
    }
  }
}

// ---------------------------------------------------------------------------
extern "C" void kernel_launch(void* const* d_in, const int* in_sizes, int n_in,
                              void* d_out, int out_size, void* d_ws, size_t ws_size,
                              hipStream_t stream) {
  const float* x  = (const float*)d_in[0];
  const float* Wq = (const float*)d_in[1];
  const float* Wk = (const float*)d_in[2];
  const float* Wv = (const float*)d_in[3];
  const float* Wu = (const float*)d_in[4];
  float* out = (float*)d_out;

  // workspace layout (bf16 elements)
  const size_t xT_elems = (size_t)8 * NPIX * CIN;      // 1,605,632
  const size_t w_elems  = (size_t)9 * OC * CIN;        // 294,912
  const size_t p_elems  = (size_t)8 * NPIX * OC;       // 12,845,056
  ushort_t* xT  = (ushort_t*)d_ws;
  ushort_t* Wbq = xT + xT_elems;
  ushort_t* Wbk = Wbq + w_elems;
  ushort_t* Wbv = Wbk + w_elems;
  __hip_bfloat16* q = (__hip_bfloat16*)(Wbv + w_elems);
  __hip_bfloat16* k = q + p_elems;
  __hip_bfloat16* v = k + p_elems;

  cast_x_kernel<<<dim3(HW, 8), 256, 0, stream>>>(x, xT);
  cast_w_kernel<<<dim3(OC, 9, 3), 64, 0, stream>>>(Wq, Wk, Wv, Wbq, Wbk, Wbv);

  dim3 cgrid(28, 4, 8);  // (row pairs, oc blocks, batch)
  conv3x3_mfma<<<cgrid, 256, 0, stream>>>(xT, Wbq, q);
  conv3x3_mfma<<<cgrid, 256, 0, stream>>>(xT, Wbk, k);
  conv3x3_mfma<<<cgrid, 256, 0, stream>>>(xT, Wbv, v);

  attn_kernel<<<dim3(NPIX, 8), 256, 0, stream>>>(q, k, v, Wu, out);
}

// Round 4
// 269.431 us; speedup vs baseline: 5.2627x; 1.9191x over previous
//
#include <hip/hip_runtime.h>
#include <hip/hip_bf16.h>

#define HW   56
#define CIN  64
#define OC   512
#define NPIX (HW * HW)   // 3136

typedef unsigned short ushort_t;
typedef __attribute__((ext_vector_type(8))) short short8;
typedef __attribute__((ext_vector_type(4))) float floatx4;

static __device__ __forceinline__ ushort_t f2bf(float f) {
  __hip_bfloat16 h = __float2bfloat16(f);
  return *(ushort_t*)&h;
}

// ---------------------------------------------------------------------------
// Prepass A: x NCHW fp32 -> xT [b][h][w][c] bf16.  Block per (h, b).
// ---------------------------------------------------------------------------
__global__ __launch_bounds__(256)
void cast_x_kernel(const float* __restrict__ x, ushort_t* __restrict__ xT) {
  __shared__ ushort_t lx[CIN * HW];   // [c][w]
  const int tid = threadIdx.x;
  const int h = blockIdx.x, b = blockIdx.y;
  for (int idx = tid; idx < CIN * HW; idx += 256) {
    int c = idx / HW, w = idx - c * HW;
    lx[idx] = f2bf(x[((size_t)(b * CIN + c) * HW + h) * HW + w]);
  }
  __syncthreads();
  ushort_t* dst = xT + ((size_t)(b * HW + h)) * HW * CIN;
  for (int i = tid; i < (CIN * HW) / 4; i += 256) {
    int e0 = i * 4;
    int w = e0 >> 6, c0 = e0 & 63;
    ushort4 o;
    o.x = lx[(c0 + 0) * HW + w];
    o.y = lx[(c0 + 1) * HW + w];
    o.z = lx[(c0 + 2) * HW + w];
    o.w = lx[(c0 + 3) * HW + w];
    ((ushort4*)dst)[i] = o;
  }
}

// ---------------------------------------------------------------------------
// Prepass B: W [oc][cin][3][3] fp32 -> Wb [tap][oc][cin] bf16 (3 tensors)
// ---------------------------------------------------------------------------
__global__ __launch_bounds__(64)
void cast_w_kernel(const float* __restrict__ W0, const float* __restrict__ W1,
                   const float* __restrict__ W2, ushort_t* __restrict__ D0,
                   ushort_t* __restrict__ D1, ushort_t* __restrict__ D2) {
  const int cin = threadIdx.x;
  const int oc = blockIdx.x, tap = blockIdx.y, sel = blockIdx.z;
  const float* W = sel == 0 ? W0 : (sel == 1 ? W1 : W2);
  ushort_t* D = sel == 0 ? D0 : (sel == 1 ? D1 : D2);
  D[((size_t)tap * OC + oc) * CIN + cin] = f2bf(W[(size_t)oc * 576 + cin * 9 + tap]);
}

// ---------------------------------------------------------------------------
// Prepass C: Wu fp32 -> bf16, IDENTITY layout.  Reference flattens attended
// as (Cq, nh) -> ci = c*8 + n, which is exactly the a2 tile's order.
// (Round-3 bug: permuting by n*64+c here was wrong.)
// ---------------------------------------------------------------------------
__global__ __launch_bounds__(512)
void cast_wu_kernel(const float* __restrict__ Wu, ushort_t* __restrict__ WuP) {
  const int co = blockIdx.x, t = threadIdx.x;
  WuP[(size_t)co * 512 + t] = f2bf(Wu[(size_t)co * 512 + t]);
}

// ---------------------------------------------------------------------------
// Kernel 1: 3x3 conv via MFMA 16x16x32 bf16 implicit GEMM.
// PERM=1: store channel index permuted o' = (oc&63)*8 + (oc>>6)  ([c][n])
// ---------------------------------------------------------------------------
#define XLS 72             // padded cin stride in x LDS tile (bf16 units)
#define XROW (58 * XLS)
#define WLS 72

template <int PERM>
__global__ __launch_bounds__(256, 3)
void conv3x3_mfma(const ushort_t* __restrict__ xT, const ushort_t* __restrict__ Wb,
                  ushort_t* __restrict__ y) {
  __shared__ __align__(16) ushort_t xl[4 * XROW];
  __shared__ __align__(16) ushort_t wl[128 * WLS];

  const int tid  = threadIdx.x;
  const int lane = tid & 63;
  const int wv   = tid >> 6;
  const int g    = blockIdx.x;
  const int ob   = blockIdx.y;
  const int b    = blockIdx.z;
  const int h0   = g * 2;
  const int l15  = lane & 15;
  const int quad = lane >> 4;

  int abase[7];
  #pragma unroll
  for (int t = 0; t < 7; ++t) {
    int pix = t * 16 + l15;
    int row = pix / HW, ww = pix - row * HW;
    abase[t] = (row * 58 + ww) * XLS + quad * 8;
  }
  int bbase[2];
  #pragma unroll
  for (int nt = 0; nt < 2; ++nt)
    bbase[nt] = (wv * 32 + nt * 16 + l15) * WLS + quad * 8;

  floatx4 acc[7][2];
  #pragma unroll
  for (int t = 0; t < 7; ++t)
    #pragma unroll
    for (int nt = 0; nt < 2; ++nt) acc[t][nt] = (floatx4){0.f, 0.f, 0.f, 0.f};

  for (int i = tid; i < (4 * XROW * 2) / 16; i += 256)
    ((uint4*)xl)[i] = (uint4){0, 0, 0, 0};
  __syncthreads();

  for (int r = 0; r < 4; ++r) {
    int gh = h0 - 1 + r;
    if (gh >= 0 && gh < HW) {
      const uint4* src = (const uint4*)(xT + ((size_t)(b * HW + gh) * HW) * CIN);
      for (int idx = tid; idx < 448; idx += 256) {
        int w = idx >> 3, co = (idx & 7) * 8;
        uint4 d = src[idx];
        *(uint4*)&xl[(r * 58 + 1 + w) * XLS + co] = d;
      }
    }
  }

  const ushort_t* wsrc_base = Wb + (size_t)ob * 128 * CIN;

  #pragma unroll
  for (int kh = 0; kh < 3; ++kh) {
    #pragma unroll
    for (int kw = 0; kw < 3; ++kw) {
      const int tap = kh * 3 + kw;
      __syncthreads();
      {
        const uint4* wsrc = (const uint4*)(wsrc_base + (size_t)tap * OC * CIN);
        #pragma unroll
        for (int i = 0; i < 4; ++i) {
          int idx = tid + i * 256;
          int oc = idx >> 3, co = (idx & 7) * 8;
          uint4 d = wsrc[idx];
          *(uint4*)&wl[oc * WLS + co] = d;
        }
      }
      __syncthreads();

      #pragma unroll
      for (int ck = 0; ck < 2; ++ck) {
        const int cko = ck * 32;
        short8 bf[2];
        #pragma unroll
        for (int nt = 0; nt < 2; ++nt)
          bf[nt] = *(const short8*)&wl[bbase[nt] + cko];
        #pragma unroll
        for (int t = 0; t < 7; ++t) {
          short8 af = *(const short8*)&xl[abase[t] + (kh * 58 + kw) * XLS + cko];
          #pragma unroll
          for (int nt = 0; nt < 2; ++nt)
            acc[t][nt] = __builtin_amdgcn_mfma_f32_16x16x32_bf16(
                af, bf[nt], acc[t][nt], 0, 0, 0);
        }
      }
    }
  }

  #pragma unroll
  for (int t = 0; t < 7; ++t) {
    #pragma unroll
    for (int r = 0; r < 4; ++r) {
      int pix = t * 16 + quad * 4 + r;
      int row = pix / HW, ww = pix - row * HW;
      size_t pb = ((size_t)((b * HW + h0 + row) * HW + ww)) * OC;
      #pragma unroll
      for (int nt = 0; nt < 2; ++nt) {
        int oc = ob * 128 + wv * 32 + nt * 16 + l15;
        int o = PERM ? ((oc & 63) * 8 + (oc >> 6)) : oc;
        y[pb + o] = f2bf(acc[t][nt][r]);
      }
    }
  }
}

// ---------------------------------------------------------------------------
// Kernel 2: MFMA channel-attention + 1x1 conv + ReLU.
// Block = 16 pixels, 4 waves; wave handles 4 pixels end-to-end, then the
// block does the out-GEMM (64co x 16px x 512).  q,k in [c][n]; v in [n][c].
// ---------------------------------------------------------------------------
#define PST  72    // P LDS stride (bf16 el): 16B-aligned rows, 2-way banks
#define A2ST 520   // a2 stride: 16B-aligned, 2-way banks

__global__ __launch_bounds__(256, 3)
void attn_kernel(const ushort_t* __restrict__ q, const ushort_t* __restrict__ k,
                 const ushort_t* __restrict__ v, const ushort_t* __restrict__ WuP,
                 float* __restrict__ out) {
  __shared__ __align__(16) ushort_t Pl[4][64 * PST];   // per-wave P[qc][kc] bf16
  __shared__ __align__(16) ushort_t a2[16 * A2ST];     // attended [pix][c*8+n] bf16

  const int tid  = threadIdx.x;
  const int lane = tid & 63;
  const int wv   = tid >> 6;
  const int l15  = lane & 15;
  const int quad = lane >> 4;
  const int p0   = blockIdx.x * 16;
  const int b    = blockIdx.y;
  const size_t ibase = ((size_t)b * NPIX + p0) * 512;

  ushort_t* Pw = &Pl[wv][0];
  const float scale = 0.044194173824159216f;  // 1/sqrt(512)

  for (int i = 0; i < 4; ++i) {
    const int plocal = wv * 4 + i;
    const ushort_t* qp = q + ibase + (size_t)plocal * 512;
    const ushort_t* kp = k + ibase + (size_t)plocal * 512;
    const ushort_t* vp = v + ibase + (size_t)plocal * 512;

    // ---- S^T[kc][qc] = k . q^T  (contraction n=8, padded in K=32 via A=0)
    floatx4 S[4][4];
    #pragma unroll
    for (int mt = 0; mt < 4; ++mt)
      #pragma unroll
      for (int nt = 0; nt < 4; ++nt) S[mt][nt] = (floatx4){0.f, 0.f, 0.f, 0.f};

    short8 bfr[4];
    #pragma unroll
    for (int nt = 0; nt < 4; ++nt)
      bfr[nt] = *(const short8*)(qp + (nt * 16 + l15) * 8);
    #pragma unroll
    for (int mt = 0; mt < 4; ++mt) {
      short8 af = (short8){0, 0, 0, 0, 0, 0, 0, 0};
      if (quad == 0) af = *(const short8*)(kp + (mt * 16 + l15) * 8);
      #pragma unroll
      for (int nt = 0; nt < 4; ++nt)
        S[mt][nt] = __builtin_amdgcn_mfma_f32_16x16x32_bf16(af, bfr[nt], S[mt][nt], 0, 0, 0);
    }

    // ---- softmax over kc per column qc = nt*16+l15 (kc spans mt,r,quad)
    #pragma unroll
    for (int nt = 0; nt < 4; ++nt) {
      float m = S[0][nt][0];
      #pragma unroll
      for (int mt = 0; mt < 4; ++mt)
        #pragma unroll
        for (int r = 0; r < 4; ++r) m = fmaxf(m, S[mt][nt][r]);
      m = fmaxf(m, __shfl_xor(m, 16));
      m = fmaxf(m, __shfl_xor(m, 32));
      float sum = 0.f;
      #pragma unroll
      for (int mt = 0; mt < 4; ++mt)
        #pragma unroll
        for (int r = 0; r < 4; ++r) {
          float e = __expf((S[mt][nt][r] - m) * scale);
          S[mt][nt][r] = e;
          sum += e;
        }
      sum += __shfl_xor(sum, 16);
      sum += __shfl_xor(sum, 32);
      float inv = __builtin_amdgcn_rcpf(sum);
      #pragma unroll
      for (int mt = 0; mt < 4; ++mt) {
        ushort4 w4;
        w4.x = f2bf(S[mt][nt][0] * inv);
        w4.y = f2bf(S[mt][nt][1] * inv);
        w4.z = f2bf(S[mt][nt][2] * inv);
        w4.w = f2bf(S[mt][nt][3] * inv);
        *(ushort4*)&Pw[(nt * 16 + l15) * PST + mt * 16 + quad * 4] = w4;
      }
    }

    // ---- attended^T[n][qc] = v^T . P^T   (M=n pad 16, N=qc 64, K=kc 64)
    floatx4 T[4];
    #pragma unroll
    for (int nt = 0; nt < 4; ++nt) T[nt] = (floatx4){0.f, 0.f, 0.f, 0.f};
    #pragma unroll
    for (int ck = 0; ck < 2; ++ck) {
      short8 av = *(const short8*)(vp + (l15 & 7) * 64 + ck * 32 + quad * 8);
      #pragma unroll
      for (int nt = 0; nt < 4; ++nt) {
        short8 pf = *(const short8*)&Pw[(nt * 16 + l15) * PST + ck * 32 + quad * 8];
        T[nt] = __builtin_amdgcn_mfma_f32_16x16x32_bf16(av, pf, T[nt], 0, 0, 0);
      }
    }
    if (quad < 2) {
      #pragma unroll
      for (int nt = 0; nt < 4; ++nt) {
        ushort4 w4;
        w4.x = f2bf(T[nt][0]);
        w4.y = f2bf(T[nt][1]);
        w4.z = f2bf(T[nt][2]);
        w4.w = f2bf(T[nt][3]);
        *(ushort4*)&a2[plocal * A2ST + (nt * 16 + l15) * 8 + quad * 4] = w4;
      }
    }
  }
  __syncthreads();

  // ---- out GEMM: M=co(wave's 16), N=16 pixels, K=512
  floatx4 O = (floatx4){0.f, 0.f, 0.f, 0.f};
  #pragma unroll
  for (int ck = 0; ck < 16; ++ck) {
    short8 aw = *(const short8*)(WuP + (size_t)(wv * 16 + l15) * 512 + ck * 32 + quad * 8);
    short8 bw = *(const short8*)&a2[l15 * A2ST + ck * 32 + quad * 8];
    O = __builtin_amdgcn_mfma_f32_16x16x32_bf16(aw, bw, O, 0, 0, 0);
  }
  #pragma unroll
  for (int r = 0; r < 4; ++r) {
    int co = wv * 16 + quad * 4 + r;
    out[((size_t)b * 64 + co) * NPIX + p0 + l15] = fmaxf(O[r], 0.f);
  }
}

// ---------------------------------------------------------------------------
extern "C" void kernel_launch(void* const* d_in, const int* in_sizes, int n_in,
                              void* d_out, int out_size, void* d_ws, size_t ws_size,
                              hipStream_t stream) {
  const float* x  = (const float*)d_in[0];
  const float* Wq = (const float*)d_in[1];
  const float* Wk = (const float*)d_in[2];
  const float* Wv = (const float*)d_in[3];
  const float* Wu = (const float*)d_in[4];
  float* out = (float*)d_out;

  const size_t xT_elems = (size_t)8 * NPIX * CIN;
  const size_t w_elems  = (size_t)9 * OC * CIN;
  const size_t wu_elems = (size_t)64 * 512;
  const size_t p_elems  = (size_t)8 * NPIX * OC;
  ushort_t* xT  = (ushort_t*)d_ws;
  ushort_t* Wbq = xT + xT_elems;
  ushort_t* Wbk = Wbq + w_elems;
  ushort_t* Wbv = Wbk + w_elems;
  ushort_t* WuP = Wbv + w_elems;
  ushort_t* q   = WuP + wu_elems;
  ushort_t* k   = q + p_elems;
  ushort_t* v   = k + p_elems;

  cast_x_kernel<<<dim3(HW, 8), 256, 0, stream>>>(x, xT);
  cast_w_kernel<<<dim3(OC, 9, 3), 64, 0, stream>>>(Wq, Wk, Wv, Wbq, Wbk, Wbv);
  cast_wu_kernel<<<64, 512, 0, stream>>>(Wu, WuP);

  dim3 cgrid(28, 4, 8);
  conv3x3_mfma<1><<<cgrid, 256, 0, stream>>>(xT, Wbq, q);
  conv3x3_mfma<1><<<cgrid, 256, 0, stream>>>(xT, Wbk, k);
  conv3x3_mfma<0><<<cgrid, 256, 0, stream>>>(xT, Wbv, v);

  attn_kernel<<<dim3(NPIX / 16, 8), 256, 0, stream>>>(q, k, v, WuP, out);
}

// Round 5
// 212.787 us; speedup vs baseline: 6.6636x; 1.2662x over previous
//
#include <hip/hip_runtime.h>
#include <hip/hip_bf16.h>

#define HW   56
#define CIN  64
#define OC   512
#define NPIX (HW * HW)   // 3136

typedef unsigned short ushort_t;
typedef __attribute__((ext_vector_type(8))) short short8;
typedef __attribute__((ext_vector_type(4))) float floatx4;

static __device__ __forceinline__ ushort_t f2bf(float f) {
  __hip_bfloat16 h = __float2bfloat16(f);
  return *(ushort_t*)&h;
}

// ---------------------------------------------------------------------------
// Prepass A: x NCHW fp32 -> xT [b][h][w][c] bf16.  Block per (h, b).
// ---------------------------------------------------------------------------
__global__ __launch_bounds__(256)
void cast_x_kernel(const float* __restrict__ x, ushort_t* __restrict__ xT) {
  __shared__ ushort_t lx[CIN * HW];   // [c][w]
  const int tid = threadIdx.x;
  const int h = blockIdx.x, b = blockIdx.y;
  for (int idx = tid; idx < CIN * HW; idx += 256) {
    int c = idx / HW, w = idx - c * HW;
    lx[idx] = f2bf(x[((size_t)(b * CIN + c) * HW + h) * HW + w]);
  }
  __syncthreads();
  ushort_t* dst = xT + ((size_t)(b * HW + h)) * HW * CIN;
  for (int i = tid; i < (CIN * HW) / 4; i += 256) {
    int e0 = i * 4;
    int w = e0 >> 6, c0 = e0 & 63;
    ushort4 o;
    o.x = lx[(c0 + 0) * HW + w];
    o.y = lx[(c0 + 1) * HW + w];
    o.z = lx[(c0 + 2) * HW + w];
    o.w = lx[(c0 + 3) * HW + w];
    ((ushort4*)dst)[i] = o;
  }
}

// ---------------------------------------------------------------------------
// Prepass B: W [oc][cin][3][3] fp32 -> Wb [tap][oc][cin] bf16 (3 tensors)
// Block per (oc, sel); lane = cin; 9-tap loop inside (block's 2.3KB W row
// stays in L1 across taps).
// ---------------------------------------------------------------------------
__global__ __launch_bounds__(64)
void cast_w_kernel(const float* __restrict__ W0, const float* __restrict__ W1,
                   const float* __restrict__ W2, ushort_t* __restrict__ D0,
                   ushort_t* __restrict__ D1, ushort_t* __restrict__ D2) {
  const int cin = threadIdx.x;
  const int oc = blockIdx.x, sel = blockIdx.y;
  const float* W = sel == 0 ? W0 : (sel == 1 ? W1 : W2);
  ushort_t* D = sel == 0 ? D0 : (sel == 1 ? D1 : D2);
  #pragma unroll
  for (int tap = 0; tap < 9; ++tap)
    D[((size_t)tap * OC + oc) * CIN + cin] = f2bf(W[(size_t)oc * 576 + cin * 9 + tap]);
}

// ---------------------------------------------------------------------------
// Prepass C: Wu fp32 -> bf16, identity layout (ci = c*8+n already matches a2).
// ---------------------------------------------------------------------------
__global__ __launch_bounds__(512)
void cast_wu_kernel(const float* __restrict__ Wu, ushort_t* __restrict__ WuP) {
  const int co = blockIdx.x, t = threadIdx.x;
  WuP[(size_t)co * 512 + t] = f2bf(Wu[(size_t)co * 512 + t]);
}

// ---------------------------------------------------------------------------
// Kernel 1: 3x3 conv via MFMA 16x16x32 bf16 implicit GEMM.
// Weights live in VGPRs (ping-pong prefetch, one tap ahead) — NO per-tap
// LDS staging, no K-loop barriers.  x tile staged once in LDS.
// PERM=1: store channel index permuted o' = (oc&63)*8 + (oc>>6)  ([c][n])
// ---------------------------------------------------------------------------
#define XLS 72             // padded cin stride in x LDS tile (bf16 units)
#define XROW (58 * XLS)

template <int PERM>
__global__ __launch_bounds__(256, 3)
void conv3x3_mfma(const ushort_t* __restrict__ xT, const ushort_t* __restrict__ Wb,
                  ushort_t* __restrict__ y) {
  __shared__ __align__(16) ushort_t xl[4 * XROW];   // 33408 B

  const int tid  = threadIdx.x;
  const int lane = tid & 63;
  const int wv   = tid >> 6;
  const int g    = blockIdx.x;
  const int ob   = blockIdx.y;
  const int b    = blockIdx.z;
  const int h0   = g * 2;
  const int l15  = lane & 15;
  const int quad = lane >> 4;

  int abase[7];
  #pragma unroll
  for (int t = 0; t < 7; ++t) {
    int pix = t * 16 + l15;
    int row = pix / HW, ww = pix - row * HW;
    abase[t] = (row * 58 + ww) * XLS + quad * 8;
  }

  // per-lane B-fragment base: this wave's 32 oc, 8 cin els at quad*8
  const ushort_t* wb0 = Wb + ((size_t)(ob * 128 + wv * 32 + l15)) * CIN + quad * 8;

  short8 Bf[2][2][2];   // [parity][ck][nt]
  #pragma unroll
  for (int ck = 0; ck < 2; ++ck)
    #pragma unroll
    for (int nt = 0; nt < 2; ++nt)
      Bf[0][ck][nt] = *(const short8*)(wb0 + (size_t)(nt * 16) * CIN + ck * 32);

  floatx4 acc[7][2];
  #pragma unroll
  for (int t = 0; t < 7; ++t)
    #pragma unroll
    for (int nt = 0; nt < 2; ++nt) acc[t][nt] = (floatx4){0.f, 0.f, 0.f, 0.f};

  // ---- zero x tile, then stage valid rows; single barrier pair
  for (int i = tid; i < (4 * XROW * 2) / 16; i += 256)
    ((uint4*)xl)[i] = (uint4){0, 0, 0, 0};
  __syncthreads();
  for (int r = 0; r < 4; ++r) {
    int gh = h0 - 1 + r;
    if (gh >= 0 && gh < HW) {
      const uint4* src = (const uint4*)(xT + ((size_t)(b * HW + gh) * HW) * CIN);
      for (int idx = tid; idx < 448; idx += 256) {
        int w = idx >> 3, co = (idx & 7) * 8;
        uint4 d = src[idx];
        *(uint4*)&xl[(r * 58 + 1 + w) * XLS + co] = d;
      }
    }
  }
  __syncthreads();

  // ---- K-loop: 9 taps, zero barriers, weights prefetched to regs
  #pragma unroll
  for (int tap = 0; tap < 9; ++tap) {
    const int p = tap & 1;
    if (tap < 8) {
      #pragma unroll
      for (int ck = 0; ck < 2; ++ck)
        #pragma unroll
        for (int nt = 0; nt < 2; ++nt)
          Bf[p ^ 1][ck][nt] =
              *(const short8*)(wb0 + ((size_t)(tap + 1) * OC + nt * 16) * CIN + ck * 32);
    }
    const int kh = tap / 3, kw = tap - kh * 3;
    #pragma unroll
    for (int ck = 0; ck < 2; ++ck) {
      #pragma unroll
      for (int t = 0; t < 7; ++t) {
        short8 af = *(const short8*)&xl[abase[t] + (kh * 58 + kw) * XLS + ck * 32];
        acc[t][0] = __builtin_amdgcn_mfma_f32_16x16x32_bf16(af, Bf[p][ck][0], acc[t][0], 0, 0, 0);
        acc[t][1] = __builtin_amdgcn_mfma_f32_16x16x32_bf16(af, Bf[p][ck][1], acc[t][1], 0, 0, 0);
      }
    }
  }

  // ---- epilogue
  #pragma unroll
  for (int t = 0; t < 7; ++t) {
    #pragma unroll
    for (int r = 0; r < 4; ++r) {
      int pix = t * 16 + quad * 4 + r;
      int row = pix / HW, ww = pix - row * HW;
      size_t pb = ((size_t)((b * HW + h0 + row) * HW + ww)) * OC;
      #pragma unroll
      for (int nt = 0; nt < 2; ++nt) {
        int oc = ob * 128 + wv * 32 + nt * 16 + l15;
        int o = PERM ? ((oc & 63) * 8 + (oc >> 6)) : oc;
        y[pb + o] = f2bf(acc[t][nt][r]);
      }
    }
  }
}

// ---------------------------------------------------------------------------
// Kernel 2: MFMA channel-attention + 1x1 conv + ReLU.
// Block = 16 pixels, 4 waves; wave handles 4 pixels (global frags prefetched
// one pixel ahead), then the block does the out-GEMM (64co x 16px x 512).
// q,k in [c][n]; v in [n][c].
// ---------------------------------------------------------------------------
#define PST  72    // P LDS stride (bf16 el): 16B-aligned rows, 2-way banks
#define A2ST 520   // a2 stride: 16B-aligned, 2-way banks

__global__ __launch_bounds__(256, 2)
void attn_kernel(const ushort_t* __restrict__ q, const ushort_t* __restrict__ k,
                 const ushort_t* __restrict__ v, const ushort_t* __restrict__ WuP,
                 float* __restrict__ out) {
  __shared__ __align__(16) ushort_t Pl[4][64 * PST];   // per-wave P[qc][kc] bf16
  __shared__ __align__(16) ushort_t a2[16 * A2ST];     // attended [pix][c*8+n] bf16

  const int tid  = threadIdx.x;
  const int lane = tid & 63;
  const int wv   = tid >> 6;
  const int l15  = lane & 15;
  const int quad = lane >> 4;
  const int p0   = blockIdx.x * 16;
  const int b    = blockIdx.y;
  const size_t ibase = ((size_t)b * NPIX + p0) * 512;

  ushort_t* Pw = &Pl[wv][0];
  const float scale = 0.044194173824159216f;  // 1/sqrt(512)

  auto loadpix = [&](int plocal, short8 qf[4], short8 kf[4], short8 vf[2]) {
    const ushort_t* qp = q + ibase + (size_t)plocal * 512;
    const ushort_t* kp = k + ibase + (size_t)plocal * 512;
    const ushort_t* vp = v + ibase + (size_t)plocal * 512;
    #pragma unroll
    for (int nt = 0; nt < 4; ++nt)
      qf[nt] = *(const short8*)(qp + (nt * 16 + l15) * 8);
    #pragma unroll
    for (int mt = 0; mt < 4; ++mt) {
      kf[mt] = (short8){0, 0, 0, 0, 0, 0, 0, 0};
      if (quad == 0) kf[mt] = *(const short8*)(kp + (mt * 16 + l15) * 8);
    }
    #pragma unroll
    for (int ck = 0; ck < 2; ++ck)
      vf[ck] = *(const short8*)(vp + (l15 & 7) * 64 + ck * 32 + quad * 8);
  };

  short8 qf[4], kf[4], vf[2];
  loadpix(wv * 4, qf, kf, vf);

  #pragma unroll
  for (int i = 0; i < 4; ++i) {
    const int plocal = wv * 4 + i;
    short8 qn[4], kn[4], vn[2];
    if (i < 3) loadpix(plocal + 1, qn, kn, vn);

    // ---- S^T[kc][qc] = k . q^T  (contraction n=8, padded in K=32 via A=0)
    floatx4 S[4][4];
    #pragma unroll
    for (int mt = 0; mt < 4; ++mt)
      #pragma unroll
      for (int nt = 0; nt < 4; ++nt) S[mt][nt] = (floatx4){0.f, 0.f, 0.f, 0.f};
    #pragma unroll
    for (int mt = 0; mt < 4; ++mt)
      #pragma unroll
      for (int nt = 0; nt < 4; ++nt)
        S[mt][nt] = __builtin_amdgcn_mfma_f32_16x16x32_bf16(kf[mt], qf[nt], S[mt][nt], 0, 0, 0);

    // ---- softmax over kc per column qc = nt*16+l15 (kc spans mt,r,quad)
    #pragma unroll
    for (int nt = 0; nt < 4; ++nt) {
      float m = S[0][nt][0];
      #pragma unroll
      for (int mt = 0; mt < 4; ++mt)
        #pragma unroll
        for (int r = 0; r < 4; ++r) m = fmaxf(m, S[mt][nt][r]);
      m = fmaxf(m, __shfl_xor(m, 16));
      m = fmaxf(m, __shfl_xor(m, 32));
      float sum = 0.f;
      #pragma unroll
      for (int mt = 0; mt < 4; ++mt)
        #pragma unroll
        for (int r = 0; r < 4; ++r) {
          float e = __expf((S[mt][nt][r] - m) * scale);
          S[mt][nt][r] = e;
          sum += e;
        }
      sum += __shfl_xor(sum, 16);
      sum += __shfl_xor(sum, 32);
      float inv = __builtin_amdgcn_rcpf(sum);
      #pragma unroll
      for (int mt = 0; mt < 4; ++mt) {
        ushort4 w4;
        w4.x = f2bf(S[mt][nt][0] * inv);
        w4.y = f2bf(S[mt][nt][1] * inv);
        w4.z = f2bf(S[mt][nt][2] * inv);
        w4.w = f2bf(S[mt][nt][3] * inv);
        *(ushort4*)&Pw[(nt * 16 + l15) * PST + mt * 16 + quad * 4] = w4;
      }
    }

    // ---- attended^T[n][qc] = v^T . P^T   (M=n pad 16, N=qc 64, K=kc 64)
    floatx4 T[4];
    #pragma unroll
    for (int nt = 0; nt < 4; ++nt) T[nt] = (floatx4){0.f, 0.f, 0.f, 0.f};
    #pragma unroll
    for (int ck = 0; ck < 2; ++ck) {
      #pragma unroll
      for (int nt = 0; nt < 4; ++nt) {
        short8 pf = *(const short8*)&Pw[(nt * 16 + l15) * PST + ck * 32 + quad * 8];
        T[nt] = __builtin_amdgcn_mfma_f32_16x16x32_bf16(vf[ck], pf, T[nt], 0, 0, 0);
      }
    }
    if (quad < 2) {
      #pragma unroll
      for (int nt = 0; nt < 4; ++nt) {
        ushort4 w4;
        w4.x = f2bf(T[nt][0]);
        w4.y = f2bf(T[nt][1]);
        w4.z = f2bf(T[nt][2]);
        w4.w = f2bf(T[nt][3]);
        *(ushort4*)&a2[plocal * A2ST + (nt * 16 + l15) * 8 + quad * 4] = w4;
      }
    }

    if (i < 3) {
      #pragma unroll
      for (int z = 0; z < 4; ++z) { qf[z] = qn[z]; kf[z] = kn[z]; }
      vf[0] = vn[0];
      vf[1] = vn[1];
    }
  }
  __syncthreads();

  // ---- out GEMM: M=co(wave's 16), N=16 pixels, K=512
  floatx4 O = (floatx4){0.f, 0.f, 0.f, 0.f};
  #pragma unroll
  for (int ck = 0; ck < 16; ++ck) {
    short8 aw = *(const short8*)(WuP + (size_t)(wv * 16 + l15) * 512 + ck * 32 + quad * 8);
    short8 bw = *(const short8*)&a2[l15 * A2ST + ck * 32 + quad * 8];
    O = __builtin_amdgcn_mfma_f32_16x16x32_bf16(aw, bw, O, 0, 0, 0);
  }
  #pragma unroll
  for (int r = 0; r < 4; ++r) {
    int co = wv * 16 + quad * 4 + r;
    out[((size_t)b * 64 + co) * NPIX + p0 + l15] = fmaxf(O[r], 0.f);
  }
}

// ---------------------------------------------------------------------------
extern "C" void kernel_launch(void* const* d_in, const int* in_sizes, int n_in,
                              void* d_out, int out_size, void* d_ws, size_t ws_size,
                              hipStream_t stream) {
  const float* x  = (const float*)d_in[0];
  const float* Wq = (const float*)d_in[1];
  const float* Wk = (const float*)d_in[2];
  const float* Wv = (const float*)d_in[3];
  const float* Wu = (const float*)d_in[4];
  float* out = (float*)d_out;

  const size_t xT_elems = (size_t)8 * NPIX * CIN;
  const size_t w_elems  = (size_t)9 * OC * CIN;
  const size_t wu_elems = (size_t)64 * 512;
  const size_t p_elems  = (size_t)8 * NPIX * OC;
  ushort_t* xT  = (ushort_t*)d_ws;
  ushort_t* Wbq = xT + xT_elems;
  ushort_t* Wbk = Wbq + w_elems;
  ushort_t* Wbv = Wbk + w_elems;
  ushort_t* WuP = Wbv + w_elems;
  ushort_t* q   = WuP + wu_elems;
  ushort_t* k   = q + p_elems;
  ushort_t* v   = k + p_elems;

  cast_x_kernel<<<dim3(HW, 8), 256, 0, stream>>>(x, xT);
  cast_w_kernel<<<dim3(OC, 3), 64, 0, stream>>>(Wq, Wk, Wv, Wbq, Wbk, Wbv);
  cast_wu_kernel<<<64, 512, 0, stream>>>(Wu, WuP);

  dim3 cgrid(28, 4, 8);
  conv3x3_mfma<1><<<cgrid, 256, 0, stream>>>(xT, Wbq, q);
  conv3x3_mfma<1><<<cgrid, 256, 0, stream>>>(xT, Wbk, k);
  conv3x3_mfma<0><<<cgrid, 256, 0, stream>>>(xT, Wbv, v);

  attn_kernel<<<dim3(NPIX / 16, 8), 256, 0, stream>>>(q, k, v, WuP, out);
}